// Round 9
// baseline (3194.266 us; speedup 1.0000x reference)
//
#include <hip/hip_runtime.h>

typedef __bf16 bf16;
typedef __bf16 bf16x8 __attribute__((ext_vector_type(8)));
typedef __bf16 bf16x4 __attribute__((ext_vector_type(4)));
typedef float  f32x4  __attribute__((ext_vector_type(4)));

#define T_LEN 70
#define BATCH 64
#define HDIM  1024
#define GDIM  4096
#define VOCAB 32000
#define TBROW (T_LEN * BATCH)   // 4480

#define MFMA16(a, b, c) __builtin_amdgcn_mfma_f32_16x16x32_bf16((a), (b), (c), 0, 0, 0)

typedef const __attribute__((address_space(1))) void gas_void;
typedef __attribute__((address_space(3))) void las_void;

// ---------------------------------------------------------------------------
__global__ void split_kernel(const float* __restrict__ w, bf16* __restrict__ hi,
                             bf16* __restrict__ lo, int n4) {
    int stride = gridDim.x * blockDim.x;
    for (int i = blockIdx.x * blockDim.x + threadIdx.x; i < n4; i += stride) {
        float4 v = reinterpret_cast<const float4*>(w)[i];
        bf16 h0 = (bf16)v.x, h1 = (bf16)v.y, h2 = (bf16)v.z, h3 = (bf16)v.w;
        bf16x4 hv = {h0, h1, h2, h3};
        bf16x4 lv = {(bf16)(v.x - (float)h0), (bf16)(v.y - (float)h1),
                     (bf16)(v.z - (float)h2), (bf16)(v.w - (float)h3)};
        reinterpret_cast<bf16x4*>(hi)[i] = hv;
        reinterpret_cast<bf16x4*>(lo)[i] = lv;
    }
}

__global__ void conv_kernel(const float* __restrict__ w, bf16* __restrict__ hi, int n4) {
    int stride = gridDim.x * blockDim.x;
    for (int i = blockIdx.x * blockDim.x + threadIdx.x; i < n4; i += stride) {
        float4 v = reinterpret_cast<const float4*>(w)[i];
        bf16x4 hv = {(bf16)v.x, (bf16)v.y, (bf16)v.z, (bf16)v.w};
        reinterpret_cast<bf16x4*>(hi)[i] = hv;
    }
}

__global__ void embed_kernel(const int* __restrict__ x, const float* __restrict__ emb,
                             bf16* __restrict__ xh, bf16* __restrict__ xl) {
    int row = blockIdx.x;
    int tok = x[row];
    const float4* src = reinterpret_cast<const float4*>(emb + (size_t)tok * HDIM);
    bf16x4* dh = reinterpret_cast<bf16x4*>(xh + (size_t)row * HDIM);
    bf16x4* dl = reinterpret_cast<bf16x4*>(xl + (size_t)row * HDIM);
    for (int i = threadIdx.x; i < HDIM / 4; i += blockDim.x) {
        float4 v = src[i];
        bf16 h0 = (bf16)v.x, h1 = (bf16)v.y, h2 = (bf16)v.z, h3 = (bf16)v.w;
        dh[i] = (bf16x4){h0, h1, h2, h3};
        dl[i] = (bf16x4){(bf16)(v.x - (float)h0), (bf16)(v.y - (float)h1),
                         (bf16)(v.z - (float)h2), (bf16)(v.w - (float)h3)};
    }
}

// initial h stored at parity 1 (first reads occur at input-parity 1)
__global__ void init_kernel(const float* __restrict__ h0, const float* __restrict__ c0,
                            bf16* __restrict__ hsb, float* __restrict__ cst) {
    int i = blockIdx.x * blockDim.x + threadIdx.x;
    int l = i >> 16, r = i & 65535;
    float v = h0[i];
    bf16 h = (bf16)v;
    hsb[(size_t)((l * 2 + 1) * 2 + 0) * 65536 + r] = h;
    hsb[(size_t)((l * 2 + 1) * 2 + 1) * 65536 + r] = (bf16)(v - (float)h);
    cst[i] = c0[i];
}

// ---------------------------------------------------------------------------
// GEMM C = sum_p A_p B_p^T + bias (unchanged from r7)
// ---------------------------------------------------------------------------
__global__ __launch_bounds__(256) void gemm_bt(
    const bf16* __restrict__ a0, const bf16* __restrict__ a1, const bf16* __restrict__ a2,
    const bf16* __restrict__ b0, const bf16* __restrict__ b1, const bf16* __restrict__ b2,
    int npass, int K, const float* __restrict__ bias, float* __restrict__ C, int ldc) {
    __shared__ __align__(16) char As[128 * 128];
    __shared__ __align__(16) char Bs[128 * 128];
    const int tid = threadIdx.x;
    const int wid = tid >> 6, lane = tid & 63;
    const int l15 = lane & 15, l4 = lane >> 4;

    const int nbx = gridDim.x, mt = gridDim.y, nwg = nbx * mt;
    const int flat = blockIdx.y * nbx + blockIdx.x;
    const int xcd = flat & 7, o8 = flat >> 3;
    const int q8 = nwg >> 3, r8 = nwg & 7;
    const int wg = (xcd < r8 ? xcd * (q8 + 1) : r8 * (q8 + 1) + (xcd - r8) * q8) + o8;
    const int m0 = (wg % mt) * 128, n0 = (wg / mt) * 128;

    const int wr = (wid >> 1) * 64, wc = (wid & 1) * 64;
    const int swz_rd = (l15 & 7) << 4;
    const int rowL = lane >> 3;
    const int colE = (((lane & 7) ^ rowL)) << 3;

    f32x4 acc[4][4];
#pragma unroll
    for (int i = 0; i < 4; ++i)
#pragma unroll
        for (int j = 0; j < 4; ++j) acc[i][j] = (f32x4){0.f, 0.f, 0.f, 0.f};

    for (int p = 0; p < npass; ++p) {
        const bf16* A = (p == 0) ? a0 : ((p == 1) ? a1 : a2);
        const bf16* B = (p == 0) ? b0 : ((p == 1) ? b1 : b2);
        for (int k0 = 0; k0 < K; k0 += 64) {
            __syncthreads();
#pragma unroll
            for (int c2 = 0; c2 < 4; ++c2) {
                const int ch = wid * 4 + c2;
                const int row = ch * 8 + rowL;
                __builtin_amdgcn_global_load_lds(
                    (gas_void*)(A + (size_t)(m0 + row) * K + k0 + colE),
                    (las_void*)(As + ch * 1024), 16, 0, 0);
                __builtin_amdgcn_global_load_lds(
                    (gas_void*)(B + (size_t)(n0 + row) * K + k0 + colE),
                    (las_void*)(Bs + ch * 1024), 16, 0, 0);
            }
            __syncthreads();
#pragma unroll
            for (int ks = 0; ks < 2; ++ks) {
                const int cb = (ks * 64 + l4 * 16) ^ swz_rd;
                bf16x8 af[4], bfr[4];
#pragma unroll
                for (int mi = 0; mi < 4; ++mi)
                    af[mi] = *reinterpret_cast<const bf16x8*>(As + (wr + mi * 16 + l15) * 128 + cb);
#pragma unroll
                for (int ni = 0; ni < 4; ++ni)
                    bfr[ni] = *reinterpret_cast<const bf16x8*>(Bs + (wc + ni * 16 + l15) * 128 + cb);
#pragma unroll
                for (int mi = 0; mi < 4; ++mi)
#pragma unroll
                    for (int ni = 0; ni < 4; ++ni)
                        acc[mi][ni] = MFMA16(af[mi], bfr[ni], acc[mi][ni]);
            }
        }
    }
#pragma unroll
    for (int ni = 0; ni < 4; ++ni) {
        const int col = n0 + wc + ni * 16 + l15;
        const float bv = bias[col];
#pragma unroll
        for (int mi = 0; mi < 4; ++mi) {
            const int row0 = m0 + wr + mi * 16 + l4 * 4;
#pragma unroll
            for (int r = 0; r < 4; ++r)
                C[(size_t)(row0 + r) * ldc + col] = acc[mi][ni][r] + bv;
        }
    }
}

// ---------------------------------------------------------------------------
// Wavefront-persistent LSTM v5: ONE barrier per chunk (24/superstep), one
// LBAR per epilogue (pex double-slot), weights+px for next superstep
// prefetched BEFORE the grid barrier (raw-barrier gbar with counted vmcnt),
// 8-way split arrival counters. Unconditional epilogue stores (dump buffer)
// keep per-wave vmcnt counts schedule-exact; WB2 handles wn-asymmetry.
// ---------------------------------------------------------------------------
__global__ __launch_bounds__(512, 1) void lstm_wave(
    const float* __restrict__ c0,
    const bf16* __restrict__ Wh0h, const bf16* __restrict__ Wh0l,
    const bf16* __restrict__ Wi1h, const bf16* __restrict__ Wi1l,
    const bf16* __restrict__ Wh1h, const bf16* __restrict__ Wh1l,
    const bf16* __restrict__ Wi2h, const bf16* __restrict__ Wi2l,
    const bf16* __restrict__ Wh2h, const bf16* __restrict__ Wh2l,
    const float* __restrict__ px0,
    const float* __restrict__ bh0, const float* __restrict__ bi1,
    const float* __restrict__ bh1, const float* __restrict__ bi2,
    const float* __restrict__ bh2,
    bf16* __restrict__ hsb, bf16* __restrict__ outh, int* __restrict__ bar,
    bf16* __restrict__ dump) {
    // buf*49152 + { A-hi [0,16K), A-lo [16K,32K), B [32K,48K) }, 3 bufs.
    // pex0 (wn0) at 147456, pex1 (wn1) at 151552; total 155648.
    __shared__ __align__(16) char smem[155648];

    const int tid = threadIdx.x;
    const int lane = tid & 63, wid = tid >> 6;
    const int l15 = lane & 15, l4 = lane >> 4;
    const int wm = wid & 3, wn = wid >> 2;
    const int j0 = blockIdx.x * 4;
    // async-staging lane geometry (pre-swizzled global source, linear LDS)
    const int lrow = lane >> 4;
    const int lp = lane & 15;
    const int rA0 = wid * 4 + lrow;
    const int rA1 = (wid + 8) * 4 + lrow;
    const size_t offA0 = (size_t)rA0 * HDIM + (size_t)((lp ^ (rA0 & 15)) * 8);
    const size_t offA1 = (size_t)rA1 * HDIM + (size_t)((lp ^ (rA1 & 15)) * 8);
    const int colrW = (wid & 3) * 4 + lrow;
    const int colgW = (colrW >> 2) * 1024 + j0 + (colrW & 3);
    const size_t offB = (size_t)colgW * HDIM + (size_t)((lp ^ (colrW & 15)) * 8);
    const int hiloW = (wid >> 2) & 1;
    const int ldsA0 = wid * 1024, ldsA1 = (wid + 8) * 1024;
    const int ldsB0 = 32768 + wid * 1024, ldsB1 = 32768 + (wid + 8) * 1024;
    // fragment reads (4-bit XOR)
    const int a_frow = (wm * 16 + l15) * 256;
    const int b_frow = l15 * 256;
    const int swz_r = l15 << 4;
    const int kb0 = wn * 128;
    // gates
    const int gb = tid >> 2, gj = tid & 3;
    const int gb64 = gb & 63;

    // gate-side biases (per quarter), c-state; then syncthreads clears scoreboard
    const float b0_0 = bh0[0 * 1024 + j0 + gj], b0_1 = bh0[1 * 1024 + j0 + gj],
                b0_2 = bh0[2 * 1024 + j0 + gj], b0_3 = bh0[3 * 1024 + j0 + gj];
    const float b1_0 = bi1[0 * 1024 + j0 + gj] + bh1[0 * 1024 + j0 + gj],
                b1_1 = bi1[1 * 1024 + j0 + gj] + bh1[1 * 1024 + j0 + gj],
                b1_2 = bi1[2 * 1024 + j0 + gj] + bh1[2 * 1024 + j0 + gj],
                b1_3 = bi1[3 * 1024 + j0 + gj] + bh1[3 * 1024 + j0 + gj];
    const float b2_0 = bi2[0 * 1024 + j0 + gj] + bh2[0 * 1024 + j0 + gj],
                b2_1 = bi2[1 * 1024 + j0 + gj] + bh2[1 * 1024 + j0 + gj],
                b2_2 = bi2[2 * 1024 + j0 + gj] + bh2[2 * 1024 + j0 + gj],
                b2_3 = bi2[3 * 1024 + j0 + gj] + bh2[3 * 1024 + j0 + gj];
    float creg0 = c0[0 * 65536 + gb64 * 1024 + j0 + gj];
    float creg1 = c0[1 * 65536 + gb64 * 1024 + j0 + gj];
    float creg2 = c0[2 * 65536 + gb64 * 1024 + j0 + gj];
    __syncthreads();   // drain all prologue loads -> clean compiler scoreboard

    auto hsp = [&](int l, int par, int hl) {
        return hsb + (((size_t)l * 2 + par) * 2 + hl) * 65536;
    };

    bf16* const nullp = nullptr;
    float pxr0, pxr1, pxr2, pxr3;
    int barid = 0;

#define WB(N)                                                                    \
    {                                                                            \
        asm volatile("s_waitcnt vmcnt(" #N ")" ::: "memory");                    \
        __builtin_amdgcn_s_barrier();                                            \
        __builtin_amdgcn_sched_barrier(0);                                       \
    }
#define WB2(N0, N1)                                                              \
    {                                                                            \
        if (wn == 0) asm volatile("s_waitcnt vmcnt(" #N0 ")" ::: "memory");      \
        else         asm volatile("s_waitcnt vmcnt(" #N1 ")" ::: "memory");      \
        __builtin_amdgcn_s_barrier();                                            \
        __builtin_amdgcn_sched_barrier(0);                                       \
    }

#define PAH(c)  ((c) < 8 ? A0h : (c) < 16 ? A1h : A2h)
#define PAL(c)  ((c) < 8 ? A0l : (c) < 16 ? A1l : A2l)
#define PB0H(c) ((c) < 8 ? Wh0h : (c) < 16 ? Wh1h : Wh2h)
#define PB0L(c) ((c) < 8 ? Wh0l : (c) < 16 ? Wh1l : Wh2l)
#define PB1H(c) ((c) < 8 ? Wi1h : Wi2h)
#define PB1L(c) ((c) < 8 ? Wi1l : Wi2l)

#define ISSUE(c, buf, TWOB)                                                      \
    {                                                                            \
        char* base_ = smem + (buf) * 49152;                                      \
        const bf16* pb0_ = hiloW ? PB0L(c) : PB0H(c);                            \
        const size_t ca_ = (size_t)(((c) & 7) * 128);                            \
        __builtin_amdgcn_global_load_lds((gas_void*)(pb0_ + offB + ca_),         \
                                         (las_void*)(base_ + ldsB0), 16, 0, 0);  \
        if (TWOB) {                                                              \
            const bf16* pb1_ = hiloW ? PB1L(c) : PB1H(c);                        \
            __builtin_amdgcn_global_load_lds((gas_void*)(pb1_ + offB + ca_),     \
                                             (las_void*)(base_ + ldsB1), 16, 0, 0); \
        }                                                                        \
        const bf16* pah_ = PAH(c);                                               \
        const bf16* pal_ = PAL(c);                                               \
        __builtin_amdgcn_global_load_lds((gas_void*)(pah_ + offA0 + ca_),        \
                                         (las_void*)(base_ + ldsA0), 16, 0, 0);  \
        __builtin_amdgcn_global_load_lds((gas_void*)(pah_ + offA1 + ca_),        \
                                         (las_void*)(base_ + ldsA1), 16, 0, 0);  \
        __builtin_amdgcn_global_load_lds((gas_void*)(pal_ + offA0 + ca_),        \
                                         (las_void*)(base_ + 16384 + ldsA0), 16, 0, 0); \
        __builtin_amdgcn_global_load_lds((gas_void*)(pal_ + offA1 + ca_),        \
                                         (las_void*)(base_ + 16384 + ldsA1), 16, 0, 0); \
    }

// weights of chunks 0..2 for NEXT superstep (s-invariant pointers): 6 loads
#define ISSUE_B3()                                                               \
    {                                                                            \
        const bf16* pb0_ = hiloW ? Wh0l : Wh0h;                                  \
        const bf16* pb1_ = hiloW ? Wi1l : Wi1h;                                  \
        _Pragma("unroll") for (int c_ = 0; c_ < 3; ++c_) {                       \
            char* base_ = smem + c_ * 49152;                                     \
            const size_t ca_ = (size_t)(c_ * 128);                               \
            __builtin_amdgcn_global_load_lds((gas_void*)(pb0_ + offB + ca_),     \
                                             (las_void*)(base_ + ldsB0), 16, 0, 0); \
            __builtin_amdgcn_global_load_lds((gas_void*)(pb1_ + offB + ca_),     \
                                             (las_void*)(base_ + ldsB1), 16, 0, 0); \
        }                                                                        \
    }

// px for superstep SS via inline-asm loads (compiler-untracked): 4 loads
#define ISSUE_PX(SS)                                                             \
    {                                                                            \
        const float* pxb_ = px0 + (size_t)(SS) * (BATCH * GDIM) +                \
                            (size_t)gb64 * GDIM + j0 + gj;                       \
        asm volatile("global_load_dword %0, %1, off" : "=v"(pxr0)                \
                     : "v"((unsigned long long)(uintptr_t)pxb_) : "memory");     \
        asm volatile("global_load_dword %0, %1, off" : "=v"(pxr1)                \
                     : "v"((unsigned long long)(uintptr_t)(pxb_ + 1024)) : "memory"); \
        asm volatile("global_load_dword %0, %1, off" : "=v"(pxr2)                \
                     : "v"((unsigned long long)(uintptr_t)(pxb_ + 2048)) : "memory"); \
        asm volatile("global_load_dword %0, %1, off" : "=v"(pxr3)                \
                     : "v"((unsigned long long)(uintptr_t)(pxb_ + 3072)) : "memory"); \
    }

// A of chunks 0..2 (group 0) for current superstep: 12 loads
#define ISSUE_A3()                                                               \
    {                                                                            \
        _Pragma("unroll") for (int c_ = 0; c_ < 3; ++c_) {                       \
            char* base_ = smem + c_ * 49152;                                     \
            const size_t e0_ = offA0 + (size_t)(c_ * 128);                       \
            const size_t e1_ = offA1 + (size_t)(c_ * 128);                       \
            __builtin_amdgcn_global_load_lds((gas_void*)(A0h + e0_),             \
                                             (las_void*)(base_ + ldsA0), 16, 0, 0); \
            __builtin_amdgcn_global_load_lds((gas_void*)(A0h + e1_),             \
                                             (las_void*)(base_ + ldsA1), 16, 0, 0); \
            __builtin_amdgcn_global_load_lds((gas_void*)(A0l + e0_),             \
                                             (las_void*)(base_ + 16384 + ldsA0), 16, 0, 0); \
            __builtin_amdgcn_global_load_lds((gas_void*)(A0l + e1_),             \
                                             (las_void*)(base_ + 16384 + ldsA1), 16, 0, 0); \
        }                                                                        \
    }

#define COMPUTE(buf, ACCX, ACCY, TWO, AX, AY)                                    \
    {                                                                            \
        const char* base_ = smem + (buf) * 49152;                                \
        const char* ah_ = base_ + a_frow;                                        \
        const char* al_ = base_ + 16384 + a_frow;                                \
        const char* bb_ = base_ + 32768 + b_frow;                                \
        _Pragma("unroll") for (int ks = 0; ks < 2; ++ks) {                       \
            const int cb = (kb0 + ks * 64 + l4 * 16) ^ swz_r;                    \
            bf16x8 a_h = *reinterpret_cast<const bf16x8*>(ah_ + cb);             \
            bf16x8 a_l = *reinterpret_cast<const bf16x8*>(al_ + cb);             \
            bf16x8 w0h = *reinterpret_cast<const bf16x8*>(bb_ + cb);             \
            bf16x8 w0l = *reinterpret_cast<const bf16x8*>(bb_ + 4096 + cb);      \
            if (AX) {                                                            \
                ACCX = MFMA16(a_h, w0h, ACCX);                                   \
                ACCX = MFMA16(a_h, w0l, ACCX);                                   \
                ACCX = MFMA16(a_l, w0h, ACCX);                                   \
            }                                                                    \
            if (TWO) {                                                           \
                bf16x8 w1h = *reinterpret_cast<const bf16x8*>(bb_ + 8192 + cb);  \
                bf16x8 w1l = *reinterpret_cast<const bf16x8*>(bb_ + 12288 + cb); \
                if (AY) {                                                        \
                    ACCY = MFMA16(a_h, w1h, ACCY);                               \
                    ACCY = MFMA16(a_h, w1l, ACCY);                               \
                    ACCY = MFMA16(a_l, w1h, ACCY);                               \
                }                                                                \
            }                                                                    \
        }                                                                        \
    }

// one LBAR; gates read both pex slots; stores ALWAYS execute (dump if inactive)
#define EPILOGUE(ACC, BQ0, BQ1, BQ2, BQ3, PXQ0, PXQ1, PXQ2, PXQ3, ACT, HH, HL, OHP, CREG) \
    {                                                                            \
        float* pexw = reinterpret_cast<float*>(smem + 147456 + wn * 4096);       \
        _Pragma("unroll") for (int r = 0; r < 4; ++r)                            \
            pexw[(wm * 16 + l4 * 4 + r) * 16 + l15] = ACC[r];                    \
        asm volatile("s_waitcnt lgkmcnt(0)" ::: "memory");                       \
        __builtin_amdgcn_s_barrier();                                            \
        __builtin_amdgcn_sched_barrier(0);                                       \
        if (tid < 256) {                                                         \
            const float* px0f = reinterpret_cast<const float*>(smem + 147456);   \
            const float* px1f = reinterpret_cast<const float*>(smem + 151552);   \
            const float pi = px0f[gb * 16 + 0 + gj] + px1f[gb * 16 + 0 + gj] + (BQ0) + (PXQ0); \
            const float pf = px0f[gb * 16 + 4 + gj] + px1f[gb * 16 + 4 + gj] + (BQ1) + (PXQ1); \
            const float po = px0f[gb * 16 + 8 + gj] + px1f[gb * 16 + 8 + gj] + (BQ2) + (PXQ2); \
            const float pg = px0f[gb * 16 + 12 + gj] + px1f[gb * 16 + 12 + gj] + (BQ3) + (PXQ3); \
            const float ig = 1.f / (1.f + expf(-pi));                            \
            const float fg = 1.f / (1.f + expf(-pf));                            \
            const float og = 1.f / (1.f + expf(-po));                            \
            const float gg = tanhf(pg);                                          \
            const float c2v = fg * (CREG) + ig * gg;                             \
            const float h2v = og * tanhf(c2v);                                   \
            if (ACT) (CREG) = c2v;                                               \
            const int idx = gb * 1024 + j0 + gj;                                 \
            const bf16 hhi = (bf16)h2v;                                          \
            (HH)[idx] = hhi;                                                     \
            (HL)[idx] = (bf16)(h2v - (float)hhi);                                \
            if ((OHP) != nullptr) (OHP)[idx] = hhi;                              \
        }                                                                        \
    }

    // -------- superstep-0 prefetch: B(6), px(4) --------
    ISSUE_B3();
    ISSUE_PX(0);

#pragma unroll 1
    for (int s = 0; s < T_LEN + 2; ++s) {
        const int ps = s & 1;
        const bool act0 = (s < T_LEN);
        const bool act1 = (s >= 1) && (s <= T_LEN);
        const bool act2 = (s >= 2);

        const bf16* A0h = hsp(0, 1 - ps, 0); const bf16* A0l = hsp(0, 1 - ps, 1);
        const bf16* A1h = hsp(1, ps, 0);     const bf16* A1l = hsp(1, ps, 1);
        const bf16* A2h = hsp(2, 1 - ps, 0); const bf16* A2l = hsp(2, 1 - ps, 1);
        bf16* dH0h = act0 ? hsp(0, ps, 0)     : dump;
        bf16* dH0l = act0 ? hsp(0, ps, 1)     : dump;
        bf16* dH1h = act1 ? hsp(1, 1 - ps, 0) : dump;
        bf16* dH1l = act1 ? hsp(1, 1 - ps, 1) : dump;
        bf16* dH2h = act2 ? hsp(2, ps, 0)     : dump;
        bf16* dH2l = act2 ? hsp(2, ps, 1)     : dump;
        bf16* ohp  = act2 ? (outh + (size_t)(s - 2) * 65536) : dump;

        // A of chunks 0..2 (12 loads) — after gbar's acquire
        ISSUE_A3();

        f32x4 acc0 = (f32x4){0.f, 0.f, 0.f, 0.f};
        f32x4 acc1 = (f32x4){0.f, 0.f, 0.f, 0.f};
        f32x4 acc2 = (f32x4){0.f, 0.f, 0.f, 0.f};

        // ---- group 0: chunks 0-7 ----
        WB(8)      COMPUTE(0, acc0, acc1, 1, act0, act1)
        WB(4)      COMPUTE(1, acc0, acc1, 1, act0, act1) ISSUE(3, 0, 1)
        WB(6)      COMPUTE(2, acc0, acc1, 1, act0, act1) ISSUE(4, 1, 1)
        WB(6)      COMPUTE(0, acc0, acc1, 1, act0, act1) ISSUE(5, 2, 1)
        WB(6)      COMPUTE(1, acc0, acc1, 1, act0, act1) ISSUE(6, 0, 1)
        WB(6)      COMPUTE(2, acc0, acc1, 1, act0, act1) ISSUE(7, 1, 1)
        WB(6)      COMPUTE(0, acc0, acc1, 1, act0, act1) ISSUE(8, 2, 1)
        WB(6)      COMPUTE(1, acc0, acc1, 1, act0, act1) ISSUE(9, 0, 1)
        EPILOGUE(acc0, b0_0, b0_1, b0_2, b0_3, pxr0, pxr1, pxr2, pxr3,
                 act0, dH0h, dH0l, nullp, creg0)
        // ---- group 1: chunks 8-15 ----
        WB2(8, 6)  COMPUTE(2, acc1, acc2, 1, act1, act2) ISSUE(10, 1, 1)
        WB2(8, 6)  COMPUTE(0, acc1, acc2, 1, act1, act2) ISSUE(11, 2, 1)
        WB(6)      COMPUTE(1, acc1, acc2, 1, act1, act2) ISSUE(12, 0, 1)
        WB(6)      COMPUTE(2, acc1, acc2, 1, act1, act2) ISSUE(13, 1, 1)
        WB(6)      COMPUTE(0, acc1, acc2, 1, act1, act2) ISSUE(14, 2, 1)
        WB(6)      COMPUTE(1, acc1, acc2, 1, act1, act2) ISSUE(15, 0, 1)
        WB(6)      COMPUTE(2, acc1, acc2, 1, act1, act2) ISSUE(16, 1, 0)
        WB(5)      COMPUTE(0, acc1, acc2, 1, act1, act2) ISSUE(17, 2, 0)
        EPILOGUE(acc1, b1_0, b1_1, b1_2, b1_3, 0.f, 0.f, 0.f, 0.f,
                 act1, dH1h, dH1l, nullp, creg1)
        // ---- group 2: chunks 16-23 ----
        WB2(7, 5)  COMPUTE(1, acc2, acc2, 0, act2, act2) ISSUE(18, 0, 0)
        WB2(7, 5)  COMPUTE(2, acc2, acc2, 0, act2, act2) ISSUE(19, 1, 0)
        WB(5)      COMPUTE(0, acc2, acc2, 0, act2, act2) ISSUE(20, 2, 0)
        WB(5)      COMPUTE(1, acc2, acc2, 0, act2, act2) ISSUE(21, 0, 0)
        WB(5)      COMPUTE(2, acc2, acc2, 0, act2, act2) ISSUE(22, 1, 0)
        WB(5)      COMPUTE(0, acc2, acc2, 0, act2, act2) ISSUE(23, 2, 0)
        WB(5)      COMPUTE(1, acc2, acc2, 0, act2, act2)
        WB(0)      COMPUTE(2, acc2, acc2, 0, act2, act2)
        EPILOGUE(acc2, b2_0, b2_1, b2_2, b2_3, 0.f, 0.f, 0.f, 0.f,
                 act2, dH2h, dH2l, ohp, creg2)

        // ---- prefetch for s+1, then grid barrier (overlapped) ----
        ISSUE_B3();
        {
            const int sn = (s + 1 < T_LEN) ? (s + 1) : 0;
            ISSUE_PX(sn);
        }
        if (s < T_LEN + 1) {
            // entry: drain only the epilogue stores (leave B+px = 10 in flight)
            asm volatile("s_waitcnt vmcnt(10)" ::: "memory");
            __builtin_amdgcn_s_barrier();
            __builtin_amdgcn_sched_barrier(0);
            if (tid == 0) {
                int* slot = bar + barid * 128 + (blockIdx.x & 7) * 16;
                __hip_atomic_fetch_add(slot, 1, __ATOMIC_RELEASE,
                                       __HIP_MEMORY_SCOPE_AGENT);
                for (;;) {
                    int sum = 0;
#pragma unroll
                    for (int k = 0; k < 8; ++k)
                        sum += __hip_atomic_load(bar + barid * 128 + k * 16,
                                                 __ATOMIC_RELAXED,
                                                 __HIP_MEMORY_SCOPE_AGENT);
                    if (sum >= (int)gridDim.x) break;
                    __builtin_amdgcn_s_sleep(2);
                }
                __builtin_amdgcn_fence(__ATOMIC_ACQUIRE, "agent");
            }
            ++barid;
            __builtin_amdgcn_s_barrier();
            __builtin_amdgcn_sched_barrier(0);
        }
    }
#undef WB
#undef WB2
#undef PAH
#undef PAL
#undef PB0H
#undef PB0L
#undef PB1H
#undef PB1L
#undef ISSUE
#undef ISSUE_B3
#undef ISSUE_PX
#undef ISSUE_A3
#undef COMPUTE
#undef EPILOGUE
}

// ---------------------------------------------------------------------------
extern "C" void kernel_launch(void* const* d_in, const int* in_sizes, int n_in,
                              void* d_out, int out_size, void* d_ws, size_t ws_size,
                              hipStream_t stream) {
    (void)in_sizes; (void)n_in; (void)out_size; (void)ws_size;
    const int*   x   = (const int*)d_in[0];
    const float* h0  = (const float*)d_in[1];
    const float* c0  = (const float*)d_in[2];
    const float* emb = (const float*)d_in[3];
    const float* W[6] = { (const float*)d_in[4],  (const float*)d_in[6],
                          (const float*)d_in[8],  (const float*)d_in[10],
                          (const float*)d_in[12], (const float*)d_in[14] };
    const float* bi0 = (const float*)d_in[5];
    const float* bh0 = (const float*)d_in[7];
    const float* bi1 = (const float*)d_in[9];
    const float* bh1 = (const float*)d_in[11];
    const float* bi2 = (const float*)d_in[13];
    const float* bh2 = (const float*)d_in[15];
    const float* Wd  = (const float*)d_in[16];
    const float* bd  = (const float*)d_in[17];

    char* ws = (char*)d_ws;
    size_t off = 0;
    float* px0 = (float*)(ws + off); off += (size_t)TBROW * GDIM * 4;
    bf16* wsp[12];
    for (int i = 0; i < 12; ++i) { wsp[i] = (bf16*)(ws + off); off += (size_t)GDIM * HDIM * 2; }
    bf16* wdb  = (bf16*)(ws + off); off += (size_t)VOCAB * HDIM * 2;
    bf16* xeh  = (bf16*)(ws + off); off += (size_t)TBROW * HDIM * 2;
    bf16* xel  = (bf16*)(ws + off); off += (size_t)TBROW * HDIM * 2;
    bf16* outh = (bf16*)(ws + off); off += (size_t)TBROW * HDIM * 2;
    bf16* hsb  = (bf16*)(ws + off); off += (size_t)12 * BATCH * HDIM * 2;
    float* cst = (float*)(ws + off); off += (size_t)3 * BATCH * HDIM * 4;
    int*  bar  = (int*)(ws + off);  off += 72 * 128 * 4;           // 8-way arrive counters
    bf16* dump = (bf16*)(ws + off); off += (size_t)BATCH * HDIM * 2;

    // wsp[0..1]=Wi0, [2..3]=Wh0, [4..5]=Wi1, [6..7]=Wh1, [8..9]=Wi2, [10..11]=Wh2
    for (int i = 0; i < 6; ++i)
        split_kernel<<<1024, 256, 0, stream>>>(W[i], wsp[2 * i], wsp[2 * i + 1],
                                               GDIM * HDIM / 4);
    conv_kernel<<<2048, 256, 0, stream>>>(Wd, wdb, VOCAB * HDIM / 4);
    embed_kernel<<<TBROW, 256, 0, stream>>>(x, emb, xeh, xel);
    init_kernel<<<768, 256, 0, stream>>>(h0, c0, hsb, cst);
    (void)hipMemsetAsync(bar, 0, 72 * 128 * 4, stream);

    // px0 = xe @ Wi0^T + bi0 (split-3)
    dim3 gpx(GDIM / 128, TBROW / 128);
    gemm_bt<<<gpx, 256, 0, stream>>>(xeh, xel, xeh, wsp[0], wsp[0], wsp[1],
                                     3, HDIM, bi0, px0, GDIM);

    // whole recurrence: wavefront-persistent, single-barrier chunks
    lstm_wave<<<256, 512, 0, stream>>>(
        c0,
        wsp[2], wsp[3],           // Wh0
        wsp[4], wsp[5],           // Wi1
        wsp[6], wsp[7],           // Wh1
        wsp[8], wsp[9],           // Wi2
        wsp[10], wsp[11],         // Wh2
        px0, bh0, bi1, bh1, bi2, bh2,
        hsb, outh, bar, dump);

    // decoder: d_out = outh @ Wd^T + bd
    dim3 gdec(VOCAB / 128, TBROW / 128);
    gemm_bt<<<gdec, 256, 0, stream>>>(outh, nullptr, nullptr, wdb, nullptr, nullptr,
                                      1, HDIM, bd, (float*)d_out, VOCAB);
}